// Round 11
// baseline (340.771 us; speedup 1.0000x reference)
//
#include <hip/hip_runtime.h>
#include <cmath>

#define DEV static __device__ __forceinline__

typedef _Float16 half8 __attribute__((ext_vector_type(8)));
typedef _Float16 half4 __attribute__((ext_vector_type(4)));
typedef float f32x4 __attribute__((ext_vector_type(4)));

DEV float warp64_sum(float v) {
    for (int o = 32; o > 0; o >>= 1) v += __shfl_xor(v, o, 64);
    return v;
}

DEV unsigned fkey(float f) {
    unsigned b = __float_as_uint(f);
    return (b & 0x80000000u) ? ~b : (b | 0x80000000u);
}
DEV float fdecode(unsigned k) {
    return (k & 0x80000000u) ? __uint_as_float(k ^ 0x80000000u) : __uint_as_float(~k);
}

// ---------------- count (+ fused edge_attr sum) ----------------
__global__ __launch_bounds__(256) void k_count(const int* __restrict__ ei,
                                               const float* __restrict__ ea,
                                               int* __restrict__ cnt,
                                               float* __restrict__ easum, int E, int Nn) {
    __shared__ float ls[4];
    float s = 0.f;
    int total = E + Nn;
    for (int i = blockIdx.x * blockDim.x + threadIdx.x; i < total; i += gridDim.x * blockDim.x) {
        int d;
        if (i < E) { d = ei[E + i]; s += ea[i]; }
        else       d = i - E;
        atomicAdd(&cnt[d], 1);
    }
    s = warp64_sum(s);
    int lane = threadIdx.x & 63, w = threadIdx.x >> 6;
    if (lane == 0) ls[w] = s;
    __syncthreads();
    if (threadIdx.x == 0) {
        float t = ls[0] + ls[1] + ls[2] + ls[3];
        if (t != 0.f) atomicAdd(easum, t);
    }
}

// ---- hierarchical exclusive scan: 1024 elems per block ----
__global__ __launch_bounds__(256) void k_scan1(const int* __restrict__ counts,
                                               int* __restrict__ offs,
                                               int* __restrict__ bsum, int n) {
    __shared__ int ls[256];
    int t = threadIdx.x;
    int base = blockIdx.x * 1024 + t * 4;
    int4 v = {0, 0, 0, 0};
    if (base + 3 < n) v = *(const int4*)&counts[base];
    else {
        if (base + 0 < n) v.x = counts[base + 0];
        if (base + 1 < n) v.y = counts[base + 1];
        if (base + 2 < n) v.z = counts[base + 2];
    }
    int s = v.x + v.y + v.z + v.w;
    ls[t] = s;
    __syncthreads();
    for (int o = 1; o < 256; o <<= 1) {
        int u = (t >= o) ? ls[t - o] : 0;
        __syncthreads();
        ls[t] += u;
        __syncthreads();
    }
    if (t == 255) bsum[blockIdx.x] = ls[255];
    int o0 = ls[t] - s;
    int o1 = o0 + v.x, o2 = o1 + v.y, o3 = o2 + v.z;
    if (base + 3 < n) { *(int4*)&offs[base] = make_int4(o0, o1, o2, o3); }
    else {
        if (base + 0 < n) offs[base + 0] = o0;
        if (base + 1 < n) offs[base + 1] = o1;
        if (base + 2 < n) offs[base + 2] = o2;
    }
}

__global__ __launch_bounds__(256) void k_scan2(int* __restrict__ bsum,
                                               int* __restrict__ offs, int nb,
                                               int total, int n) {
    __shared__ int ls[256];
    int t = threadIdx.x;
    int s = (t < nb) ? bsum[t] : 0;
    ls[t] = s;
    __syncthreads();
    for (int o = 1; o < 256; o <<= 1) {
        int u = (t >= o) ? ls[t - o] : 0;
        __syncthreads();
        ls[t] += u;
        __syncthreads();
    }
    if (t < nb) bsum[t] = ls[t] - s;      // exclusive block prefix
    if (t == 0) offs[n] = total;
}

__global__ __launch_bounds__(256) void k_scan3(int* __restrict__ offs,
                                               const int* __restrict__ bsum, int n) {
    int add = bsum[blockIdx.x];
    if (add == 0) return;
    int i = blockIdx.x * 1024 + threadIdx.x * 4;
    if (i + 3 < n) {
        int4 v = *(int4*)&offs[i];
        v.x += add; v.y += add; v.z += add; v.w += add;
        *(int4*)&offs[i] = v;
    } else {
        for (int j = 0; j < 4 && i + j < n; ++j) offs[i + j] += add;
    }
}

__global__ void k_scatter(const int* __restrict__ ei, const float* __restrict__ ea,
                          const float* __restrict__ easum, const int* __restrict__ offs,
                          int* __restrict__ cur, int* __restrict__ csrc,
                          float* __restrict__ cea, int E, int Nn) {
    float eam = easum[0] / (float)E;
    int total = E + Nn;
    for (int i = blockIdx.x * blockDim.x + threadIdx.x; i < total; i += gridDim.x * blockDim.x) {
        int s, d; float v;
        if (i < E) { s = ei[i]; d = ei[E + i]; v = ea[i]; }
        else       { s = d = i - E; v = eam; }
        int pos = offs[d] + atomicAdd(&cur[d], 1);
        csrc[pos] = s;
        cea[pos] = v;
    }
}

// ---------------- edge coefficient ----------------
__global__ __launch_bounds__(256) void k_coef(const float* __restrict__ we0, const float* __restrict__ ae0,
                                              const float* __restrict__ we1, const float* __restrict__ ae1,
                                              const float* __restrict__ we2, const float* __restrict__ ae2,
                                              float* __restrict__ coef) {
    int t = threadIdx.x, h = t >> 6, lane = t & 63;
    const float* we[3] = {we0, we1, we2};
    const float* ae[3] = {ae0, ae1, ae2};
#pragma unroll
    for (int l = 0; l < 3; ++l) {
        float p = we[l][t] * ae[l][t];
        p = warp64_sum(p);
        if (lane == 0) coef[l * 4 + h] = p;
    }
}

// ---------------- BN affine precompute: v = res*sA + sB ----------------
__global__ __launch_bounds__(256) void k_prep(
    const float* __restrict__ b0, const float* __restrict__ g0, const float* __restrict__ be0,
    const float* __restrict__ m0, const float* __restrict__ v0,
    const float* __restrict__ b1, const float* __restrict__ g1, const float* __restrict__ be1,
    const float* __restrict__ m1, const float* __restrict__ v1,
    const float* __restrict__ b2, const float* __restrict__ g2, const float* __restrict__ be2,
    const float* __restrict__ m2, const float* __restrict__ v2,
    float* __restrict__ sAB) {
    int t = threadIdx.x;
    {
        float rs = rsqrtf(v0[t] + 1e-5f) * g0[t];
        sAB[t] = rs;
        sAB[256 + t] = (b0[t] - m0[t]) * rs + be0[t];
    }
    {
        float rs = rsqrtf(v1[t] + 1e-5f) * g1[t];
        sAB[512 + t] = rs;
        sAB[768 + t] = (b1[t] - m1[t]) * rs + be1[t];
    }
    if (t < 64) {
        float rs = rsqrtf(v2[t] + 1e-5f) * g2[t];
        sAB[1024 + t] = rs;
        sAB[1088 + t] = (b2[t] - m2[t]) * rs + be2[t];
    }
}

// ---------------- converters: fp32 -> fp16 ----------------
__global__ __launch_bounds__(256) void k_cvt_x(const float* __restrict__ x,
                                               _Float16* __restrict__ xh,
                                               int nvalid_rows, int cols, int total) {
    int i = blockIdx.x * 256 + threadIdx.x;
    if (i >= total) return;
    int r = i / cols;
    xh[i] = (r < nvalid_rows) ? (_Float16)x[i] : (_Float16)0.f;
}

// all three transposed fp16 weight tensors in one launch
__global__ __launch_bounds__(256) void k_cvt_w3(const float* __restrict__ w0,
                                                const float* __restrict__ w1,
                                                const float* __restrict__ w2,
                                                _Float16* __restrict__ wt0,
                                                _Float16* __restrict__ wt1,
                                                _Float16* __restrict__ wt2) {
    const int S0 = 256 * 32, S1 = 256 * 256;
    int i = blockIdx.x * 256 + threadIdx.x;
    if (i < S0) {
        int c = i / 32, k = i - c * 32;
        wt0[i] = (_Float16)w0[k * 256 + c];
    } else if (i < S0 + S1) {
        int j = i - S0;
        int c = j / 256, k = j - c * 256;
        wt1[j] = (_Float16)w1[k * 256 + c];
    } else if (i < S0 + 2 * S1) {
        int j = i - S0 - S1;
        int c = j / 256, k = j - c * 256;
        wt2[j] = (_Float16)w2[k * 256 + c];
    }
}

// ---------------- MFMA GEMM: Out[N,256] = A[N,K] @ W[K,256]
// A fp16 [Npad,K] staged into padded LDS tile (64 rows); Wt fp16 [256,K]
// (transposed) direct from global (L2-hot); Out fp16; fused fp32 ssrc/sdst.
template <int KT>
__global__ __launch_bounds__(256) void k_gemm_mfma(const _Float16* __restrict__ A,
                                                   const _Float16* __restrict__ Wt,
                                                   _Float16* __restrict__ Out, int nrows,
                                                   const float* __restrict__ as_,
                                                   const float* __restrict__ ad_,
                                                   float* __restrict__ ssrc,
                                                   float* __restrict__ sdst) {
    constexpr int STRIDE = KT + 8;          // halfs
    __shared__ _Float16 As[64 * STRIDE];
    const int tid = threadIdx.x;
    const int lane = tid & 63, wc = tid >> 6;
    const int l15 = lane & 15, g = lane >> 4;
    const int row0 = blockIdx.x * 64;

    // stage A tile [64][KT] -> LDS (coalesced 16B loads, padded rows)
    {
        constexpr int CPR = KT / 8;          // 16B chunks per row
        constexpr int CHUNKS = 64 * CPR;
#pragma unroll
        for (int c = tid; c < CHUNKS; c += 256) {
            int r = c / CPR;
            int kc = (c - r * CPR) * 8;
            half8 v = *(const half8*)(A + (size_t)(row0 + r) * KT + kc);
            *(half8*)(As + r * STRIDE + kc) = v;
        }
    }
    __syncthreads();

    f32x4 acc[4][4] = {};   // [m-frag][n-frag]
    const _Float16* Wb = Wt + (size_t)(wc * 64 + l15) * KT + g * 8;
    const _Float16* Ab = As + l15 * STRIDE + g * 8;

#pragma unroll
    for (int kk = 0; kk < KT; kk += 32) {
        half8 af[4], bf[4];
#pragma unroll
        for (int m = 0; m < 4; ++m)
            af[m] = *(const half8*)(Ab + m * 16 * STRIDE + kk);
#pragma unroll
        for (int f = 0; f < 4; ++f)
            bf[f] = *(const half8*)(Wb + (size_t)f * 16 * KT + kk);
#pragma unroll
        for (int m = 0; m < 4; ++m)
#pragma unroll
            for (int f = 0; f < 4; ++f)
                acc[m][f] = __builtin_amdgcn_mfma_f32_16x16x32_f16(af[m], bf[f], acc[m][f], 0, 0, 0);
    }

    float asv[4], adv[4];
#pragma unroll
    for (int f = 0; f < 4; ++f) {
        asv[f] = as_[wc * 64 + f * 16 + l15];
        adv[f] = ad_[wc * 64 + f * 16 + l15];
    }

#pragma unroll
    for (int m = 0; m < 4; ++m) {
        float ps[4] = {}, pd[4] = {};
#pragma unroll
        for (int f = 0; f < 4; ++f)
#pragma unroll
            for (int j = 0; j < 4; ++j) {
                ps[j] = fmaf(acc[m][f][j], asv[f], ps[j]);
                pd[j] = fmaf(acc[m][f][j], adv[f], pd[j]);
            }
#pragma unroll
        for (int o = 1; o < 16; o <<= 1)
#pragma unroll
            for (int j = 0; j < 4; ++j) {
                ps[j] += __shfl_xor(ps[j], o, 64);
                pd[j] += __shfl_xor(pd[j], o, 64);
            }
        if (l15 == 0) {
#pragma unroll
            for (int j = 0; j < 4; ++j) {
                int r = row0 + m * 16 + g * 4 + j;
                if (r < nrows) {
                    ssrc[r * 4 + wc] = ps[j];
                    sdst[r * 4 + wc] = pd[j];
                }
            }
        }
#pragma unroll
        for (int f = 0; f < 4; ++f)
#pragma unroll
            for (int j = 0; j < 4; ++j) {
                int r = row0 + m * 16 + g * 4 + j;
                if (r < nrows)
                    Out[(size_t)r * 256 + wc * 64 + f * 16 + l15] = (_Float16)acc[m][f][j];
            }
    }
}

// ---------------- fused softmax + aggregation: HALF-WAVE per node ----------------
// 32 lanes own one node; lane handles 8 contiguous channels (one 16B half8 load
// per gathered row). head h = l32>>3, slot s = l32&7. Two alpha registers
// (slots s, s+8) cover deg<=16 branch-free with clamped loads (pk==0 kills
// k>=deg). 8-lane shfl_xor softmax reductions. deg>16: serial online fallback.
template <bool MEAN>
__global__ __launch_bounds__(256) void k_agg(const _Float16* __restrict__ hlin,
                                             const int* __restrict__ offs,
                                             const int* __restrict__ csrc,
                                             const float* __restrict__ cea,
                                             const float* __restrict__ ssrc,
                                             const float* __restrict__ sdst,
                                             const float* __restrict__ coef,
                                             const float* __restrict__ sA,
                                             const float* __restrict__ sB,
                                             _Float16* __restrict__ outh,
                                             float* __restrict__ outf, int Nn) {
    int n = blockIdx.x * 8 + (threadIdx.x >> 5);
    if (n >= Nn) return;
    int l32 = threadIdx.x & 31;
    int halfbase = threadIdx.x & 32;      // half-wave base within the wave
    int h = l32 >> 3, s = l32 & 7;
    int b = offs[n], e = offs[n + 1];
    int deg = e - b;
    float sd = sdst[n * 4 + h], cf = coef[h];
    const _Float16* hrow = hlin + l32 * 8;

    float acc[8] = {};
    float inv;

    if (deg <= 16) {
        // wave-parallel softmax over 2x8 slots, p0/p1 stay in registers
        float a0 = -INFINITY, a1 = -INFINITY;
        if (s < deg) {
            int i = b + s;
            float a = ssrc[csrc[i] * 4 + h] + sd + cf * cea[i];
            a0 = a > 0.f ? a : 0.2f * a;                  // leaky_relu 0.2
        }
        if (s + 8 < deg) {
            int i = b + s + 8;
            float a = ssrc[csrc[i] * 4 + h] + sd + cf * cea[i];
            a1 = a > 0.f ? a : 0.2f * a;
        }
        float m = fmaxf(a0, a1);
#pragma unroll
        for (int o = 1; o < 8; o <<= 1) m = fmaxf(m, __shfl_xor(m, o, 64));
        float p0 = (s < deg) ? __expf(a0 - m) : 0.f;
        float p1 = (s + 8 < deg) ? __expf(a1 - m) : 0.f;
        float den = p0 + p1;
#pragma unroll
        for (int o = 1; o < 8; o <<= 1) den += __shfl_xor(den, o, 64);
        inv = 1.f / den;

        // batch 1: edges 0..7, unconditional clamped 16B loads
        {
            half8 hv[8];
#pragma unroll
            for (int k = 0; k < 8; ++k) {
                int kc = k < deg ? k : deg - 1;
                hv[k] = *(const half8*)(hrow + (size_t)csrc[b + kc] * 256);
            }
#pragma unroll
            for (int k = 0; k < 8; ++k) {
                float pk = __shfl(p0, halfbase + (h << 3) + k, 64);
#pragma unroll
                for (int j = 0; j < 8; ++j) acc[j] = fmaf(pk, (float)hv[k][j], acc[j]);
            }
        }
        // batch 2: edges 8..15 (only if needed)
        if (deg > 8) {
            half8 hv[8];
#pragma unroll
            for (int k = 0; k < 8; ++k) {
                int kk = 8 + k;
                int kc = kk < deg ? kk : deg - 1;
                hv[k] = *(const half8*)(hrow + (size_t)csrc[b + kc] * 256);
            }
#pragma unroll
            for (int k = 0; k < 8; ++k) {
                float pk = __shfl(p1, halfbase + (h << 3) + k, 64);
#pragma unroll
                for (int j = 0; j < 8; ++j) acc[j] = fmaf(pk, (float)hv[k][j], acc[j]);
            }
        }
    } else {
        // rare fallback: serial online softmax
        float m = -INFINITY, den = 0.f;
        for (int i = b; i < e; ++i) {
            int sn = csrc[i];
            float a = ssrc[sn * 4 + h] + sd + cf * cea[i];
            a = a > 0.f ? a : 0.2f * a;
            float mn = fmaxf(m, a);
            float sc = __expf(m - mn);
            float p = __expf(a - mn);
            den = den * sc + p;
            half8 hv = *(const half8*)(hrow + (size_t)sn * 256);
#pragma unroll
            for (int j = 0; j < 8; ++j) acc[j] = acc[j] * sc + p * (float)hv[j];
            m = mn;
        }
        inv = 1.f / den;
    }

    if (!MEAN) {
        int c = l32 * 8;
        half8 o;
#pragma unroll
        for (int j = 0; j < 8; ++j) {
            float v = acc[j] * inv * sA[c + j] + sB[c + j];
            v = v > 0.f ? v : expm1f(v);                  // ELU
            o[j] = (_Float16)v;
        }
        *(half8*)(outh + (size_t)n * 256 + c) = o;
    } else {
        float r[8];
#pragma unroll
        for (int j = 0; j < 8; ++j) {
            r[j] = acc[j] * inv;
            r[j] += __shfl_xor(r[j], 8, 64);
            r[j] += __shfl_xor(r[j], 16, 64);             // sum over 4 heads
        }
        if (l32 < 8) {
            int c = l32 * 8;
#pragma unroll
            for (int j = 0; j < 8; ++j) {
                float v = 0.25f * r[j] * sA[c + j] + sB[c + j];
                outf[(size_t)n * 64 + c + j] = v;
            }
        }
    }
}

// ---------------- graph pooling: segmented (batch is sorted) ----------------
__global__ __launch_bounds__(256) void k_pool(const float* __restrict__ h2,
                                              const int* __restrict__ batch,
                                              float* __restrict__ psum,
                                              unsigned* __restrict__ pmaxk,
                                              float* __restrict__ pcnt, int Nn) {
    int wglob = blockIdx.x * 4 + (threadIdx.x >> 6);
    int lane = threadIdx.x & 63;
    int nwaves = gridDim.x * 4;
    int span = (Nn + nwaves - 1) / nwaves;
    int b = wglob * span, e = min(b + span, Nn);
    if (b >= e) return;
    int curg = batch[b];
    float s = 0.f, mx = -INFINITY;
    float cnt = 0.f;
    for (int i = b; i < e; ++i) {
        int g = batch[i];
        float v = h2[(size_t)i * 64 + lane];
        if (g != curg) {
            atomicAdd(&psum[curg * 64 + lane], s);
            atomicMax(&pmaxk[curg * 64 + lane], fkey(mx));
            if (lane == 0) atomicAdd(&pcnt[curg], cnt);
            s = 0.f; mx = -INFINITY; cnt = 0.f; curg = g;
        }
        s += v; mx = fmaxf(mx, v); cnt += 1.f;
    }
    atomicAdd(&psum[curg * 64 + lane], s);
    atomicMax(&pmaxk[curg * 64 + lane], fkey(mx));
    if (lane == 0) atomicAdd(&pcnt[curg], cnt);
}

// ---------------- MLP head ----------------
__global__ __launch_bounds__(128) void k_mlp(const float* __restrict__ psum,
                                             const unsigned* __restrict__ pmaxk,
                                             const float* __restrict__ pcnt,
                                             const float* __restrict__ emb,
                                             const int* __restrict__ cids,
                                             const float* __restrict__ mw1, const float* __restrict__ mb1,
                                             const float* __restrict__ mw2, const float* __restrict__ mb2,
                                             const float* __restrict__ mw3, const float* __restrict__ mb3,
                                             float* __restrict__ out) {
    __shared__ float comb[144];
    __shared__ float z1[128];
    __shared__ float z2[64];
    int g = blockIdx.x, t = threadIdx.x;
    float cnt = fmaxf(pcnt[g], 1.f);
    if (t < 64) {
        comb[t] = psum[g * 64 + t] / cnt;
        comb[64 + t] = fdecode(pmaxk[g * 64 + t]);
    }
    if (t < 16) comb[128 + t] = emb[cids[g] * 16 + t];
    __syncthreads();
    float a = mb1[t];
    for (int k = 0; k < 144; ++k) a = fmaf(comb[k], mw1[k * 128 + t], a);
    z1[t] = fmaxf(a, 0.f);
    __syncthreads();
    if (t < 64) {
        float a2 = mb2[t];
        for (int k = 0; k < 128; ++k) a2 = fmaf(z1[k], mw2[k * 64 + t], a2);
        z2[t] = fmaxf(a2, 0.f);
    }
    __syncthreads();
    if (t < 2) {
        float a3 = mb3[t];
        for (int k = 0; k < 64; ++k) a3 = fmaf(z2[k], mw3[k * 2 + t], a3);
        out[g * 2 + t] = a3;
    }
}

extern "C" void kernel_launch(void* const* d_in, const int* in_sizes, int n_in,
                              void* d_out, int out_size, void* d_ws, size_t ws_size,
                              hipStream_t stream) {
    const float* x         = (const float*)d_in[0];
    const float* edge_attr = (const float*)d_in[1];
    const float* w0  = (const float*)d_in[2];
    const float* as0 = (const float*)d_in[3];
    const float* ad0 = (const float*)d_in[4];
    const float* we0 = (const float*)d_in[5];
    const float* ae0 = (const float*)d_in[6];
    const float* w1  = (const float*)d_in[7];
    const float* as1 = (const float*)d_in[8];
    const float* ad1 = (const float*)d_in[9];
    const float* we1 = (const float*)d_in[10];
    const float* ae1 = (const float*)d_in[11];
    const float* w2  = (const float*)d_in[12];
    const float* as2 = (const float*)d_in[13];
    const float* ad2 = (const float*)d_in[14];
    const float* we2 = (const float*)d_in[15];
    const float* ae2 = (const float*)d_in[16];
    const float* b0  = (const float*)d_in[17];
    const float* b1  = (const float*)d_in[18];
    const float* b2  = (const float*)d_in[19];
    const float* bn_g0 = (const float*)d_in[20];
    const float* bn_b0 = (const float*)d_in[21];
    const float* bn_m0 = (const float*)d_in[22];
    const float* bn_v0 = (const float*)d_in[23];
    const float* bn_g1 = (const float*)d_in[24];
    const float* bn_b1 = (const float*)d_in[25];
    const float* bn_m1 = (const float*)d_in[26];
    const float* bn_v1 = (const float*)d_in[27];
    const float* bn_g2 = (const float*)d_in[28];
    const float* bn_b2 = (const float*)d_in[29];
    const float* bn_m2 = (const float*)d_in[30];
    const float* bn_v2 = (const float*)d_in[31];
    const float* emb = (const float*)d_in[32];
    const float* mw1 = (const float*)d_in[33];
    const float* mb1 = (const float*)d_in[34];
    const float* mw2 = (const float*)d_in[35];
    const float* mb2 = (const float*)d_in[36];
    const float* mw3 = (const float*)d_in[37];
    const float* mb3 = (const float*)d_in[38];
    const int* edge_index = (const int*)d_in[39];
    const int* batch      = (const int*)d_in[40];
    const int* cids       = (const int*)d_in[41];

    const int N = in_sizes[40];       // 50000
    const int E = in_sizes[1];        // 300000
    const int G = in_sizes[41];       // 128
    const int EP = E + N;
    const int NB = (N + 63) / 64;     // gemm blocks
    const int Npad = NB * 64;         // padded rows
    const int NSB = (N + 1023) / 1024; // scan blocks (<=256)

    // ---- workspace layout ----
    size_t off = 0;
    auto alloc = [&](size_t bytes) -> void* {
        void* p = (char*)d_ws + off;
        off += (bytes + 255) & ~(size_t)255;
        return p;
    };
    // zero-init prefix
    int*      counts = (int*)alloc((size_t)N * 4);
    int*      cursor = (int*)alloc((size_t)N * 4);
    float*    psum   = (float*)alloc((size_t)G * 64 * 4);
    unsigned* pmaxk  = (unsigned*)alloc((size_t)G * 64 * 4);
    float*    pcnt   = (float*)alloc((size_t)G * 4);
    float*    easum  = (float*)alloc(4);
    size_t zbytes = off;
    // rest
    int*   offs = (int*)alloc((size_t)(N + 1) * 4);
    int*   bsum = (int*)alloc(256 * 4);
    int*   csrc = (int*)alloc((size_t)EP * 4);
    float* cea  = (float*)alloc((size_t)EP * 4);
    float* ssrc = (float*)alloc((size_t)N * 4 * 4);
    float* sdst = (float*)alloc((size_t)N * 4 * 4);
    float* coef = (float*)alloc(12 * 4);
    float* sAB  = (float*)alloc(1152 * 4);
    _Float16* xh  = (_Float16*)alloc((size_t)Npad * 32 * 2);
    _Float16* wt0 = (_Float16*)alloc((size_t)256 * 32 * 2);
    _Float16* wt1 = (_Float16*)alloc((size_t)256 * 256 * 2);
    _Float16* wt2 = (_Float16*)alloc((size_t)256 * 256 * 2);
    _Float16* hH  = (_Float16*)alloc((size_t)Npad * 256 * 2);  // GEMM out (fp16, gather src)
    _Float16* hB  = (_Float16*)alloc((size_t)Npad * 256 * 2);  // agg out (fp16, GEMM in)
    float*    h2  = (float*)alloc((size_t)N * 64 * 4);         // layer-2 out
    (void)ws_size; (void)n_in; (void)out_size;

    hipMemsetAsync(d_ws, 0, zbytes, stream);

    // ---- graph preprocessing ----
    k_count<<<1024, 256, 0, stream>>>(edge_index, edge_attr, counts, easum, E, N);
    k_scan1<<<NSB, 256, 0, stream>>>(counts, offs, bsum, N);
    k_scan2<<<1, 256, 0, stream>>>(bsum, offs, NSB, EP, N);
    k_scan3<<<NSB, 256, 0, stream>>>(offs, bsum, N);
    k_scatter<<<1024, 256, 0, stream>>>(edge_index, edge_attr, easum, offs, cursor, csrc, cea, E, N);
    k_coef<<<1, 256, 0, stream>>>(we0, ae0, we1, ae1, we2, ae2, coef);
    k_prep<<<1, 256, 0, stream>>>(b0, bn_g0, bn_b0, bn_m0, bn_v0,
                                  b1, bn_g1, bn_b1, bn_m1, bn_v1,
                                  b2, bn_g2, bn_b2, bn_m2, bn_v2, sAB);

    // ---- fp16 conversions ----
    {
        int tot = Npad * 32;
        k_cvt_x<<<(tot + 255) / 256, 256, 0, stream>>>(x, xh, N, 32, tot);
        int wtot = 256 * 32 + 2 * 256 * 256;
        k_cvt_w3<<<(wtot + 255) / 256, 256, 0, stream>>>(w0, w1, w2, wt0, wt1, wt2);
    }

    int agg_grid = (N + 7) / 8;

    // ---- layer 0 ----
    k_gemm_mfma<32><<<NB, 256, 0, stream>>>(xh, wt0, hH, N, as0, ad0, ssrc, sdst);
    k_agg<false><<<agg_grid, 256, 0, stream>>>(hH, offs, csrc, cea, ssrc, sdst, coef + 0,
                                               sAB, sAB + 256, hB, nullptr, N);
    // ---- layer 1 ----
    k_gemm_mfma<256><<<NB, 256, 0, stream>>>(hB, wt1, hH, N, as1, ad1, ssrc, sdst);
    k_agg<false><<<agg_grid, 256, 0, stream>>>(hH, offs, csrc, cea, ssrc, sdst, coef + 4,
                                               sAB + 512, sAB + 768, hB, nullptr, N);
    // ---- layer 2 ----
    k_gemm_mfma<256><<<NB, 256, 0, stream>>>(hB, wt2, hH, N, as2, ad2, ssrc, sdst);
    k_agg<true><<<agg_grid, 256, 0, stream>>>(hH, offs, csrc, cea, ssrc, sdst, coef + 8,
                                              sAB + 1024, sAB + 1088, nullptr, h2, N);

    // ---- pooling + MLP head ----
    k_pool<<<512, 256, 0, stream>>>(h2, batch, psum, pmaxk, pcnt, N);
    k_mlp<<<G, 128, 0, stream>>>(psum, pmaxk, pcnt, emb, cids,
                                 mw1, mb1, mw2, mb2, mw3, mb3, (float*)d_out);
}

// Round 12
// 282.048 us; speedup vs baseline: 1.2082x; 1.2082x over previous
//
#include <hip/hip_runtime.h>
#include <cmath>

#define DEV static __device__ __forceinline__

typedef _Float16 half8 __attribute__((ext_vector_type(8)));
typedef _Float16 half4 __attribute__((ext_vector_type(4)));
typedef float f32x4 __attribute__((ext_vector_type(4)));

DEV float warp64_sum(float v) {
    for (int o = 32; o > 0; o >>= 1) v += __shfl_xor(v, o, 64);
    return v;
}

DEV unsigned fkey(float f) {
    unsigned b = __float_as_uint(f);
    return (b & 0x80000000u) ? ~b : (b | 0x80000000u);
}
DEV float fdecode(unsigned k) {
    return (k & 0x80000000u) ? __uint_as_float(k ^ 0x80000000u) : __uint_as_float(~k);
}

// ---------------- count (+ fused edge_attr sum) ----------------
__global__ __launch_bounds__(256) void k_count(const int* __restrict__ ei,
                                               const float* __restrict__ ea,
                                               int* __restrict__ cnt,
                                               float* __restrict__ easum, int E, int Nn) {
    __shared__ float ls[4];
    float s = 0.f;
    int total = E + Nn;
    for (int i = blockIdx.x * blockDim.x + threadIdx.x; i < total; i += gridDim.x * blockDim.x) {
        int d;
        if (i < E) { d = ei[E + i]; s += ea[i]; }
        else       d = i - E;
        atomicAdd(&cnt[d], 1);
    }
    s = warp64_sum(s);
    int lane = threadIdx.x & 63, w = threadIdx.x >> 6;
    if (lane == 0) ls[w] = s;
    __syncthreads();
    if (threadIdx.x == 0) {
        float t = ls[0] + ls[1] + ls[2] + ls[3];
        if (t != 0.f) atomicAdd(easum, t);
    }
}

// ---- hierarchical exclusive scan: 1024 elems per block ----
__global__ __launch_bounds__(256) void k_scan1(const int* __restrict__ counts,
                                               int* __restrict__ offs,
                                               int* __restrict__ bsum, int n) {
    __shared__ int ls[256];
    int t = threadIdx.x;
    int base = blockIdx.x * 1024 + t * 4;
    int4 v = {0, 0, 0, 0};
    if (base + 3 < n) v = *(const int4*)&counts[base];
    else {
        if (base + 0 < n) v.x = counts[base + 0];
        if (base + 1 < n) v.y = counts[base + 1];
        if (base + 2 < n) v.z = counts[base + 2];
    }
    int s = v.x + v.y + v.z + v.w;
    ls[t] = s;
    __syncthreads();
    for (int o = 1; o < 256; o <<= 1) {
        int u = (t >= o) ? ls[t - o] : 0;
        __syncthreads();
        ls[t] += u;
        __syncthreads();
    }
    if (t == 255) bsum[blockIdx.x] = ls[255];
    int o0 = ls[t] - s;
    int o1 = o0 + v.x, o2 = o1 + v.y, o3 = o2 + v.z;
    if (base + 3 < n) { *(int4*)&offs[base] = make_int4(o0, o1, o2, o3); }
    else {
        if (base + 0 < n) offs[base + 0] = o0;
        if (base + 1 < n) offs[base + 1] = o1;
        if (base + 2 < n) offs[base + 2] = o2;
    }
}

__global__ __launch_bounds__(256) void k_scan2(int* __restrict__ bsum,
                                               int* __restrict__ offs, int nb,
                                               int total, int n) {
    __shared__ int ls[256];
    int t = threadIdx.x;
    int s = (t < nb) ? bsum[t] : 0;
    ls[t] = s;
    __syncthreads();
    for (int o = 1; o < 256; o <<= 1) {
        int u = (t >= o) ? ls[t - o] : 0;
        __syncthreads();
        ls[t] += u;
        __syncthreads();
    }
    if (t < nb) bsum[t] = ls[t] - s;      // exclusive block prefix
    if (t == 0) offs[n] = total;
}

__global__ __launch_bounds__(256) void k_scan3(int* __restrict__ offs,
                                               const int* __restrict__ bsum, int n) {
    int add = bsum[blockIdx.x];
    if (add == 0) return;
    int i = blockIdx.x * 1024 + threadIdx.x * 4;
    if (i + 3 < n) {
        int4 v = *(int4*)&offs[i];
        v.x += add; v.y += add; v.z += add; v.w += add;
        *(int4*)&offs[i] = v;
    } else {
        for (int j = 0; j < 4 && i + j < n; ++j) offs[i + j] += add;
    }
}

__global__ void k_scatter(const int* __restrict__ ei, const float* __restrict__ ea,
                          const float* __restrict__ easum, const int* __restrict__ offs,
                          int* __restrict__ cur, int* __restrict__ csrc,
                          float* __restrict__ cea, int E, int Nn) {
    float eam = easum[0] / (float)E;
    int total = E + Nn;
    for (int i = blockIdx.x * blockDim.x + threadIdx.x; i < total; i += gridDim.x * blockDim.x) {
        int s, d; float v;
        if (i < E) { s = ei[i]; d = ei[E + i]; v = ea[i]; }
        else       { s = d = i - E; v = eam; }
        int pos = offs[d] + atomicAdd(&cur[d], 1);
        csrc[pos] = s;
        cea[pos] = v;
    }
}

// ---------------- edge coefficient ----------------
__global__ __launch_bounds__(256) void k_coef(const float* __restrict__ we0, const float* __restrict__ ae0,
                                              const float* __restrict__ we1, const float* __restrict__ ae1,
                                              const float* __restrict__ we2, const float* __restrict__ ae2,
                                              float* __restrict__ coef) {
    int t = threadIdx.x, h = t >> 6, lane = t & 63;
    const float* we[3] = {we0, we1, we2};
    const float* ae[3] = {ae0, ae1, ae2};
#pragma unroll
    for (int l = 0; l < 3; ++l) {
        float p = we[l][t] * ae[l][t];
        p = warp64_sum(p);
        if (lane == 0) coef[l * 4 + h] = p;
    }
}

// ---------------- BN affine precompute: v = res*sA + sB ----------------
__global__ __launch_bounds__(256) void k_prep(
    const float* __restrict__ b0, const float* __restrict__ g0, const float* __restrict__ be0,
    const float* __restrict__ m0, const float* __restrict__ v0,
    const float* __restrict__ b1, const float* __restrict__ g1, const float* __restrict__ be1,
    const float* __restrict__ m1, const float* __restrict__ v1,
    const float* __restrict__ b2, const float* __restrict__ g2, const float* __restrict__ be2,
    const float* __restrict__ m2, const float* __restrict__ v2,
    float* __restrict__ sAB) {
    int t = threadIdx.x;
    {
        float rs = rsqrtf(v0[t] + 1e-5f) * g0[t];
        sAB[t] = rs;
        sAB[256 + t] = (b0[t] - m0[t]) * rs + be0[t];
    }
    {
        float rs = rsqrtf(v1[t] + 1e-5f) * g1[t];
        sAB[512 + t] = rs;
        sAB[768 + t] = (b1[t] - m1[t]) * rs + be1[t];
    }
    if (t < 64) {
        float rs = rsqrtf(v2[t] + 1e-5f) * g2[t];
        sAB[1024 + t] = rs;
        sAB[1088 + t] = (b2[t] - m2[t]) * rs + be2[t];
    }
}

// ---------------- converters: fp32 -> fp16 ----------------
__global__ __launch_bounds__(256) void k_cvt_x(const float* __restrict__ x,
                                               _Float16* __restrict__ xh,
                                               int nvalid_rows, int cols, int total) {
    int i = blockIdx.x * 256 + threadIdx.x;
    if (i >= total) return;
    int r = i / cols;
    xh[i] = (r < nvalid_rows) ? (_Float16)x[i] : (_Float16)0.f;
}

// all three transposed fp16 weight tensors in one launch
__global__ __launch_bounds__(256) void k_cvt_w3(const float* __restrict__ w0,
                                                const float* __restrict__ w1,
                                                const float* __restrict__ w2,
                                                _Float16* __restrict__ wt0,
                                                _Float16* __restrict__ wt1,
                                                _Float16* __restrict__ wt2) {
    const int S0 = 256 * 32, S1 = 256 * 256;
    int i = blockIdx.x * 256 + threadIdx.x;
    if (i < S0) {
        int c = i / 32, k = i - c * 32;
        wt0[i] = (_Float16)w0[k * 256 + c];
    } else if (i < S0 + S1) {
        int j = i - S0;
        int c = j / 256, k = j - c * 256;
        wt1[j] = (_Float16)w1[k * 256 + c];
    } else if (i < S0 + 2 * S1) {
        int j = i - S0 - S1;
        int c = j / 256, k = j - c * 256;
        wt2[j] = (_Float16)w2[k * 256 + c];
    }
}

// ---------------- MFMA GEMM: Out[N,256] = A[N,K] @ W[K,256]
// A fp16 [Npad,K] staged into padded LDS tile (64 rows); Wt fp16 [256,K]
// (transposed) direct from global (L2-hot); Out fp16; fused fp32 ssrc/sdst.
template <int KT>
__global__ __launch_bounds__(256) void k_gemm_mfma(const _Float16* __restrict__ A,
                                                   const _Float16* __restrict__ Wt,
                                                   _Float16* __restrict__ Out, int nrows,
                                                   const float* __restrict__ as_,
                                                   const float* __restrict__ ad_,
                                                   float* __restrict__ ssrc,
                                                   float* __restrict__ sdst) {
    constexpr int STRIDE = KT + 8;          // halfs
    __shared__ _Float16 As[64 * STRIDE];
    const int tid = threadIdx.x;
    const int lane = tid & 63, wc = tid >> 6;
    const int l15 = lane & 15, g = lane >> 4;
    const int row0 = blockIdx.x * 64;

    // stage A tile [64][KT] -> LDS (coalesced 16B loads, padded rows)
    {
        constexpr int CPR = KT / 8;          // 16B chunks per row
        constexpr int CHUNKS = 64 * CPR;
#pragma unroll
        for (int c = tid; c < CHUNKS; c += 256) {
            int r = c / CPR;
            int kc = (c - r * CPR) * 8;
            half8 v = *(const half8*)(A + (size_t)(row0 + r) * KT + kc);
            *(half8*)(As + r * STRIDE + kc) = v;
        }
    }
    __syncthreads();

    f32x4 acc[4][4] = {};   // [m-frag][n-frag]
    const _Float16* Wb = Wt + (size_t)(wc * 64 + l15) * KT + g * 8;
    const _Float16* Ab = As + l15 * STRIDE + g * 8;

#pragma unroll
    for (int kk = 0; kk < KT; kk += 32) {
        half8 af[4], bf[4];
#pragma unroll
        for (int m = 0; m < 4; ++m)
            af[m] = *(const half8*)(Ab + m * 16 * STRIDE + kk);
#pragma unroll
        for (int f = 0; f < 4; ++f)
            bf[f] = *(const half8*)(Wb + (size_t)f * 16 * KT + kk);
#pragma unroll
        for (int m = 0; m < 4; ++m)
#pragma unroll
            for (int f = 0; f < 4; ++f)
                acc[m][f] = __builtin_amdgcn_mfma_f32_16x16x32_f16(af[m], bf[f], acc[m][f], 0, 0, 0);
    }

    float asv[4], adv[4];
#pragma unroll
    for (int f = 0; f < 4; ++f) {
        asv[f] = as_[wc * 64 + f * 16 + l15];
        adv[f] = ad_[wc * 64 + f * 16 + l15];
    }

#pragma unroll
    for (int m = 0; m < 4; ++m) {
        float ps[4] = {}, pd[4] = {};
#pragma unroll
        for (int f = 0; f < 4; ++f)
#pragma unroll
            for (int j = 0; j < 4; ++j) {
                ps[j] = fmaf(acc[m][f][j], asv[f], ps[j]);
                pd[j] = fmaf(acc[m][f][j], adv[f], pd[j]);
            }
#pragma unroll
        for (int o = 1; o < 16; o <<= 1)
#pragma unroll
            for (int j = 0; j < 4; ++j) {
                ps[j] += __shfl_xor(ps[j], o, 64);
                pd[j] += __shfl_xor(pd[j], o, 64);
            }
        if (l15 == 0) {
#pragma unroll
            for (int j = 0; j < 4; ++j) {
                int r = row0 + m * 16 + g * 4 + j;
                if (r < nrows) {
                    ssrc[r * 4 + wc] = ps[j];
                    sdst[r * 4 + wc] = pd[j];
                }
            }
        }
#pragma unroll
        for (int f = 0; f < 4; ++f)
#pragma unroll
            for (int j = 0; j < 4; ++j) {
                int r = row0 + m * 16 + g * 4 + j;
                if (r < nrows)
                    Out[(size_t)r * 256 + wc * 64 + f * 16 + l15] = (_Float16)acc[m][f][j];
            }
    }
}

// ---------------- fused softmax + aggregation: ONE NODE PER WAVE ----------------
// Fast path (deg<=16): wave-parallel softmax (p in register); gather via
//   fully-unrolled batches of 8 UNCONDITIONAL clamped loads (pk==0 kills
//   k>=deg). Batch-2 loads (deg>8, wave-uniform branch) are HOISTED before
//   batch-1 FMAs so up to 16 loads are in flight.
// Slow path (deg>16, ~0.1%): serial online softmax (wave-uniform branch).
template <bool MEAN>
__global__ __launch_bounds__(256) void k_agg(const _Float16* __restrict__ hlin,
                                             const int* __restrict__ offs,
                                             const int* __restrict__ csrc,
                                             const float* __restrict__ cea,
                                             const float* __restrict__ ssrc,
                                             const float* __restrict__ sdst,
                                             const float* __restrict__ coef,
                                             const float* __restrict__ sA,
                                             const float* __restrict__ sB,
                                             _Float16* __restrict__ outh,
                                             float* __restrict__ outf, int Nn) {
    int n = blockIdx.x * 4 + (threadIdx.x >> 6);
    if (n >= Nn) return;
    int lane = threadIdx.x & 63;
    int h = lane >> 4, s = lane & 15;
    int b = offs[n], e = offs[n + 1];
    int deg = e - b;
    float sd = sdst[n * 4 + h], cf = coef[h];
    const _Float16* hrow = hlin + lane * 4;

    f32x4 acc = {};
    float inv;

    if (deg <= 16) {
        // wave-parallel softmax, p stays in register
        float a0 = -INFINITY;
        if (s < deg) {
            int i = b + s;
            float a = ssrc[csrc[i] * 4 + h] + sd + cf * cea[i];
            a0 = a > 0.f ? a : 0.2f * a;                  // leaky_relu 0.2
        }
        float m = a0;
#pragma unroll
        for (int o = 1; o < 16; o <<= 1) m = fmaxf(m, __shfl_xor(m, o, 64));
        float p = (s < deg) ? __expf(a0 - m) : 0.f;
        float den = p;
#pragma unroll
        for (int o = 1; o < 16; o <<= 1) den += __shfl_xor(den, o, 64);
        inv = 1.f / den;

        bool big = deg > 8;                 // wave-uniform
        half4 hv[8], hv2[8];
        // batch-1 loads: edges 0..7, unconditional clamped
#pragma unroll
        for (int k = 0; k < 8; ++k) {
            int kc = k < deg ? k : deg - 1;
            hv[k] = *(const half4*)(hrow + (size_t)csrc[b + kc] * 256);
        }
        // batch-2 loads hoisted before batch-1 FMAs (only if deg>8)
        if (big) {
#pragma unroll
            for (int k = 0; k < 8; ++k) {
                int kk = 8 + k;
                int kc = kk < deg ? kk : deg - 1;
                hv2[k] = *(const half4*)(hrow + (size_t)csrc[b + kc] * 256);
            }
        }
        // batch-1 FMAs
#pragma unroll
        for (int k = 0; k < 8; ++k) {
            float pk = __shfl(p, (h << 4) | k, 64);
#pragma unroll
            for (int j = 0; j < 4; ++j) acc[j] = fmaf(pk, (float)hv[k][j], acc[j]);
        }
        // batch-2 FMAs
        if (big) {
#pragma unroll
            for (int k = 0; k < 8; ++k) {
                float pk = __shfl(p, (h << 4) | (8 + k), 64);
#pragma unroll
                for (int j = 0; j < 4; ++j) acc[j] = fmaf(pk, (float)hv2[k][j], acc[j]);
            }
        }
    } else {
        // rare fallback: serial online softmax
        float m = -INFINITY, den = 0.f;
        for (int i = b; i < e; ++i) {
            int sn = csrc[i];
            float a = ssrc[sn * 4 + h] + sd + cf * cea[i];
            a = a > 0.f ? a : 0.2f * a;
            float mn = fmaxf(m, a);
            float sc = __expf(m - mn);
            float p = __expf(a - mn);
            den = den * sc + p;
            half4 hv = *(const half4*)(hrow + (size_t)sn * 256);
#pragma unroll
            for (int j = 0; j < 4; ++j) acc[j] = acc[j] * sc + p * (float)hv[j];
            m = mn;
        }
        inv = 1.f / den;
    }

    if (!MEAN) {
        int c = lane * 4;
        float4 a4 = *(const float4*)&sA[c];
        float4 b4 = *(const float4*)&sB[c];
        half4 o;
#pragma unroll
        for (int j = 0; j < 4; ++j) {
            float v = acc[j] * inv * (&a4.x)[j] + (&b4.x)[j];
            v = v > 0.f ? v : expm1f(v);                  // ELU
            o[j] = (_Float16)v;
        }
        *(half4*)(outh + (size_t)n * 256 + c) = o;
    } else {
        float r[4];
#pragma unroll
        for (int j = 0; j < 4; ++j) {
            r[j] = acc[j] * inv;
            r[j] += __shfl_xor(r[j], 16, 64);
            r[j] += __shfl_xor(r[j], 32, 64);             // sum over 4 heads
        }
        if (lane < 16) {
            int c = lane * 4;
#pragma unroll
            for (int j = 0; j < 4; ++j) {
                float v = 0.25f * r[j] * sA[c + j] + sB[c + j];
                outf[(size_t)n * 64 + c + j] = v;
            }
        }
    }
}

// ---------------- graph pooling: segmented (batch is sorted) ----------------
__global__ __launch_bounds__(256) void k_pool(const float* __restrict__ h2,
                                              const int* __restrict__ batch,
                                              float* __restrict__ psum,
                                              unsigned* __restrict__ pmaxk,
                                              float* __restrict__ pcnt, int Nn) {
    int wglob = blockIdx.x * 4 + (threadIdx.x >> 6);
    int lane = threadIdx.x & 63;
    int nwaves = gridDim.x * 4;
    int span = (Nn + nwaves - 1) / nwaves;
    int b = wglob * span, e = min(b + span, Nn);
    if (b >= e) return;
    int curg = batch[b];
    float s = 0.f, mx = -INFINITY;
    float cnt = 0.f;
    for (int i = b; i < e; ++i) {
        int g = batch[i];
        float v = h2[(size_t)i * 64 + lane];
        if (g != curg) {
            atomicAdd(&psum[curg * 64 + lane], s);
            atomicMax(&pmaxk[curg * 64 + lane], fkey(mx));
            if (lane == 0) atomicAdd(&pcnt[curg], cnt);
            s = 0.f; mx = -INFINITY; cnt = 0.f; curg = g;
        }
        s += v; mx = fmaxf(mx, v); cnt += 1.f;
    }
    atomicAdd(&psum[curg * 64 + lane], s);
    atomicMax(&pmaxk[curg * 64 + lane], fkey(mx));
    if (lane == 0) atomicAdd(&pcnt[curg], cnt);
}

// ---------------- MLP head ----------------
__global__ __launch_bounds__(128) void k_mlp(const float* __restrict__ psum,
                                             const unsigned* __restrict__ pmaxk,
                                             const float* __restrict__ pcnt,
                                             const float* __restrict__ emb,
                                             const int* __restrict__ cids,
                                             const float* __restrict__ mw1, const float* __restrict__ mb1,
                                             const float* __restrict__ mw2, const float* __restrict__ mb2,
                                             const float* __restrict__ mw3, const float* __restrict__ mb3,
                                             float* __restrict__ out) {
    __shared__ float comb[144];
    __shared__ float z1[128];
    __shared__ float z2[64];
    int g = blockIdx.x, t = threadIdx.x;
    float cnt = fmaxf(pcnt[g], 1.f);
    if (t < 64) {
        comb[t] = psum[g * 64 + t] / cnt;
        comb[64 + t] = fdecode(pmaxk[g * 64 + t]);
    }
    if (t < 16) comb[128 + t] = emb[cids[g] * 16 + t];
    __syncthreads();
    float a = mb1[t];
    for (int k = 0; k < 144; ++k) a = fmaf(comb[k], mw1[k * 128 + t], a);
    z1[t] = fmaxf(a, 0.f);
    __syncthreads();
    if (t < 64) {
        float a2 = mb2[t];
        for (int k = 0; k < 128; ++k) a2 = fmaf(z1[k], mw2[k * 64 + t], a2);
        z2[t] = fmaxf(a2, 0.f);
    }
    __syncthreads();
    if (t < 2) {
        float a3 = mb3[t];
        for (int k = 0; k < 64; ++k) a3 = fmaf(z2[k], mw3[k * 2 + t], a3);
        out[g * 2 + t] = a3;
    }
}

extern "C" void kernel_launch(void* const* d_in, const int* in_sizes, int n_in,
                              void* d_out, int out_size, void* d_ws, size_t ws_size,
                              hipStream_t stream) {
    const float* x         = (const float*)d_in[0];
    const float* edge_attr = (const float*)d_in[1];
    const float* w0  = (const float*)d_in[2];
    const float* as0 = (const float*)d_in[3];
    const float* ad0 = (const float*)d_in[4];
    const float* we0 = (const float*)d_in[5];
    const float* ae0 = (const float*)d_in[6];
    const float* w1  = (const float*)d_in[7];
    const float* as1 = (const float*)d_in[8];
    const float* ad1 = (const float*)d_in[9];
    const float* we1 = (const float*)d_in[10];
    const float* ae1 = (const float*)d_in[11];
    const float* w2  = (const float*)d_in[12];
    const float* as2 = (const float*)d_in[13];
    const float* ad2 = (const float*)d_in[14];
    const float* we2 = (const float*)d_in[15];
    const float* ae2 = (const float*)d_in[16];
    const float* b0  = (const float*)d_in[17];
    const float* b1  = (const float*)d_in[18];
    const float* b2  = (const float*)d_in[19];
    const float* bn_g0 = (const float*)d_in[20];
    const float* bn_b0 = (const float*)d_in[21];
    const float* bn_m0 = (const float*)d_in[22];
    const float* bn_v0 = (const float*)d_in[23];
    const float* bn_g1 = (const float*)d_in[24];
    const float* bn_b1 = (const float*)d_in[25];
    const float* bn_m1 = (const float*)d_in[26];
    const float* bn_v1 = (const float*)d_in[27];
    const float* bn_g2 = (const float*)d_in[28];
    const float* bn_b2 = (const float*)d_in[29];
    const float* bn_m2 = (const float*)d_in[30];
    const float* bn_v2 = (const float*)d_in[31];
    const float* emb = (const float*)d_in[32];
    const float* mw1 = (const float*)d_in[33];
    const float* mb1 = (const float*)d_in[34];
    const float* mw2 = (const float*)d_in[35];
    const float* mb2 = (const float*)d_in[36];
    const float* mw3 = (const float*)d_in[37];
    const float* mb3 = (const float*)d_in[38];
    const int* edge_index = (const int*)d_in[39];
    const int* batch      = (const int*)d_in[40];
    const int* cids       = (const int*)d_in[41];

    const int N = in_sizes[40];       // 50000
    const int E = in_sizes[1];        // 300000
    const int G = in_sizes[41];       // 128
    const int EP = E + N;
    const int NB = (N + 63) / 64;     // gemm blocks
    const int Npad = NB * 64;         // padded rows
    const int NSB = (N + 1023) / 1024; // scan blocks (<=256)

    // ---- workspace layout ----
    size_t off = 0;
    auto alloc = [&](size_t bytes) -> void* {
        void* p = (char*)d_ws + off;
        off += (bytes + 255) & ~(size_t)255;
        return p;
    };
    // zero-init prefix
    int*      counts = (int*)alloc((size_t)N * 4);
    int*      cursor = (int*)alloc((size_t)N * 4);
    float*    psum   = (float*)alloc((size_t)G * 64 * 4);
    unsigned* pmaxk  = (unsigned*)alloc((size_t)G * 64 * 4);
    float*    pcnt   = (float*)alloc((size_t)G * 4);
    float*    easum  = (float*)alloc(4);
    size_t zbytes = off;
    // rest
    int*   offs = (int*)alloc((size_t)(N + 1) * 4);
    int*   bsum = (int*)alloc(256 * 4);
    int*   csrc = (int*)alloc((size_t)EP * 4);
    float* cea  = (float*)alloc((size_t)EP * 4);
    float* ssrc = (float*)alloc((size_t)N * 4 * 4);
    float* sdst = (float*)alloc((size_t)N * 4 * 4);
    float* coef = (float*)alloc(12 * 4);
    float* sAB  = (float*)alloc(1152 * 4);
    _Float16* xh  = (_Float16*)alloc((size_t)Npad * 32 * 2);
    _Float16* wt0 = (_Float16*)alloc((size_t)256 * 32 * 2);
    _Float16* wt1 = (_Float16*)alloc((size_t)256 * 256 * 2);
    _Float16* wt2 = (_Float16*)alloc((size_t)256 * 256 * 2);
    _Float16* hH  = (_Float16*)alloc((size_t)Npad * 256 * 2);  // GEMM out (fp16, gather src)
    _Float16* hB  = (_Float16*)alloc((size_t)Npad * 256 * 2);  // agg out (fp16, GEMM in)
    float*    h2  = (float*)alloc((size_t)N * 64 * 4);         // layer-2 out
    (void)ws_size; (void)n_in; (void)out_size;

    hipMemsetAsync(d_ws, 0, zbytes, stream);

    // ---- graph preprocessing ----
    k_count<<<1024, 256, 0, stream>>>(edge_index, edge_attr, counts, easum, E, N);
    k_scan1<<<NSB, 256, 0, stream>>>(counts, offs, bsum, N);
    k_scan2<<<1, 256, 0, stream>>>(bsum, offs, NSB, EP, N);
    k_scan3<<<NSB, 256, 0, stream>>>(offs, bsum, N);
    k_scatter<<<1024, 256, 0, stream>>>(edge_index, edge_attr, easum, offs, cursor, csrc, cea, E, N);
    k_coef<<<1, 256, 0, stream>>>(we0, ae0, we1, ae1, we2, ae2, coef);
    k_prep<<<1, 256, 0, stream>>>(b0, bn_g0, bn_b0, bn_m0, bn_v0,
                                  b1, bn_g1, bn_b1, bn_m1, bn_v1,
                                  b2, bn_g2, bn_b2, bn_m2, bn_v2, sAB);

    // ---- fp16 conversions ----
    {
        int tot = Npad * 32;
        k_cvt_x<<<(tot + 255) / 256, 256, 0, stream>>>(x, xh, N, 32, tot);
        int wtot = 256 * 32 + 2 * 256 * 256;
        k_cvt_w3<<<(wtot + 255) / 256, 256, 0, stream>>>(w0, w1, w2, wt0, wt1, wt2);
    }

    int agg_grid = (N + 3) / 4;

    // ---- layer 0 ----
    k_gemm_mfma<32><<<NB, 256, 0, stream>>>(xh, wt0, hH, N, as0, ad0, ssrc, sdst);
    k_agg<false><<<agg_grid, 256, 0, stream>>>(hH, offs, csrc, cea, ssrc, sdst, coef + 0,
                                               sAB, sAB + 256, hB, nullptr, N);
    // ---- layer 1 ----
    k_gemm_mfma<256><<<NB, 256, 0, stream>>>(hB, wt1, hH, N, as1, ad1, ssrc, sdst);
    k_agg<false><<<agg_grid, 256, 0, stream>>>(hH, offs, csrc, cea, ssrc, sdst, coef + 4,
                                               sAB + 512, sAB + 768, hB, nullptr, N);
    // ---- layer 2 ----
    k_gemm_mfma<256><<<NB, 256, 0, stream>>>(hB, wt2, hH, N, as2, ad2, ssrc, sdst);
    k_agg<true><<<agg_grid, 256, 0, stream>>>(hH, offs, csrc, cea, ssrc, sdst, coef + 8,
                                              sAB + 1024, sAB + 1088, nullptr, h2, N);

    // ---- pooling + MLP head ----
    k_pool<<<512, 256, 0, stream>>>(h2, batch, psum, pmaxk, pcnt, N);
    k_mlp<<<G, 128, 0, stream>>>(psum, pmaxk, pcnt, emb, cids,
                                 mw1, mb1, mw2, mb2, mw3, mb3, (float*)d_out);
}

// Round 13
// 279.630 us; speedup vs baseline: 1.2186x; 1.0086x over previous
//
#include <hip/hip_runtime.h>
#include <cmath>

#define DEV static __device__ __forceinline__

typedef _Float16 half8 __attribute__((ext_vector_type(8)));
typedef _Float16 half4 __attribute__((ext_vector_type(4)));
typedef float f32x4 __attribute__((ext_vector_type(4)));

DEV float warp64_sum(float v) {
    for (int o = 32; o > 0; o >>= 1) v += __shfl_xor(v, o, 64);
    return v;
}

DEV unsigned fkey(float f) {
    unsigned b = __float_as_uint(f);
    return (b & 0x80000000u) ? ~b : (b | 0x80000000u);
}
DEV float fdecode(unsigned k) {
    return (k & 0x80000000u) ? __uint_as_float(k ^ 0x80000000u) : __uint_as_float(~k);
}

// ---------------- count (+ fused edge_attr sum) ----------------
__global__ __launch_bounds__(256) void k_count(const int* __restrict__ ei,
                                               const float* __restrict__ ea,
                                               int* __restrict__ cnt,
                                               float* __restrict__ easum, int E, int Nn) {
    __shared__ float ls[4];
    float s = 0.f;
    int total = E + Nn;
    for (int i = blockIdx.x * blockDim.x + threadIdx.x; i < total; i += gridDim.x * blockDim.x) {
        int d;
        if (i < E) { d = ei[E + i]; s += ea[i]; }
        else       d = i - E;
        atomicAdd(&cnt[d], 1);
    }
    s = warp64_sum(s);
    int lane = threadIdx.x & 63, w = threadIdx.x >> 6;
    if (lane == 0) ls[w] = s;
    __syncthreads();
    if (threadIdx.x == 0) {
        float t = ls[0] + ls[1] + ls[2] + ls[3];
        if (t != 0.f) atomicAdd(easum, t);
    }
}

// ---- hierarchical exclusive scan: 1024 elems per block ----
__global__ __launch_bounds__(256) void k_scan1(const int* __restrict__ counts,
                                               int* __restrict__ offs,
                                               int* __restrict__ bsum, int n) {
    __shared__ int ls[256];
    int t = threadIdx.x;
    int base = blockIdx.x * 1024 + t * 4;
    int4 v = {0, 0, 0, 0};
    if (base + 3 < n) v = *(const int4*)&counts[base];
    else {
        if (base + 0 < n) v.x = counts[base + 0];
        if (base + 1 < n) v.y = counts[base + 1];
        if (base + 2 < n) v.z = counts[base + 2];
    }
    int s = v.x + v.y + v.z + v.w;
    ls[t] = s;
    __syncthreads();
    for (int o = 1; o < 256; o <<= 1) {
        int u = (t >= o) ? ls[t - o] : 0;
        __syncthreads();
        ls[t] += u;
        __syncthreads();
    }
    if (t == 255) bsum[blockIdx.x] = ls[255];
    int o0 = ls[t] - s;
    int o1 = o0 + v.x, o2 = o1 + v.y, o3 = o2 + v.z;
    if (base + 3 < n) { *(int4*)&offs[base] = make_int4(o0, o1, o2, o3); }
    else {
        if (base + 0 < n) offs[base + 0] = o0;
        if (base + 1 < n) offs[base + 1] = o1;
        if (base + 2 < n) offs[base + 2] = o2;
    }
}

__global__ __launch_bounds__(256) void k_scan2(int* __restrict__ bsum,
                                               int* __restrict__ offs, int nb,
                                               int total, int n) {
    __shared__ int ls[256];
    int t = threadIdx.x;
    int s = (t < nb) ? bsum[t] : 0;
    ls[t] = s;
    __syncthreads();
    for (int o = 1; o < 256; o <<= 1) {
        int u = (t >= o) ? ls[t - o] : 0;
        __syncthreads();
        ls[t] += u;
        __syncthreads();
    }
    if (t < nb) bsum[t] = ls[t] - s;      // exclusive block prefix
    if (t == 0) offs[n] = total;
}

__global__ __launch_bounds__(256) void k_scan3(int* __restrict__ offs,
                                               const int* __restrict__ bsum, int n) {
    int add = bsum[blockIdx.x];
    if (add == 0) return;
    int i = blockIdx.x * 1024 + threadIdx.x * 4;
    if (i + 3 < n) {
        int4 v = *(int4*)&offs[i];
        v.x += add; v.y += add; v.z += add; v.w += add;
        *(int4*)&offs[i] = v;
    } else {
        for (int j = 0; j < 4 && i + j < n; ++j) offs[i + j] += add;
    }
}

__global__ void k_scatter(const int* __restrict__ ei, const float* __restrict__ ea,
                          const float* __restrict__ easum, const int* __restrict__ offs,
                          int* __restrict__ cur, int* __restrict__ csrc,
                          float* __restrict__ cea, int E, int Nn) {
    float eam = easum[0] / (float)E;
    int total = E + Nn;
    for (int i = blockIdx.x * blockDim.x + threadIdx.x; i < total; i += gridDim.x * blockDim.x) {
        int s, d; float v;
        if (i < E) { s = ei[i]; d = ei[E + i]; v = ea[i]; }
        else       { s = d = i - E; v = eam; }
        int pos = offs[d] + atomicAdd(&cur[d], 1);
        csrc[pos] = s;
        cea[pos] = v;
    }
}

// ---------------- edge coefficient + BN affine precompute (merged) ----------------
__global__ __launch_bounds__(256) void k_coef_prep(
    const float* __restrict__ we0, const float* __restrict__ ae0,
    const float* __restrict__ we1, const float* __restrict__ ae1,
    const float* __restrict__ we2, const float* __restrict__ ae2,
    float* __restrict__ coef,
    const float* __restrict__ b0, const float* __restrict__ g0, const float* __restrict__ be0,
    const float* __restrict__ m0, const float* __restrict__ v0,
    const float* __restrict__ b1, const float* __restrict__ g1, const float* __restrict__ be1,
    const float* __restrict__ m1, const float* __restrict__ v1,
    const float* __restrict__ b2, const float* __restrict__ g2, const float* __restrict__ be2,
    const float* __restrict__ m2, const float* __restrict__ v2,
    float* __restrict__ sAB) {
    int t = threadIdx.x, h = t >> 6, lane = t & 63;
    const float* we[3] = {we0, we1, we2};
    const float* ae[3] = {ae0, ae1, ae2};
#pragma unroll
    for (int l = 0; l < 3; ++l) {
        float p = we[l][t] * ae[l][t];
        p = warp64_sum(p);
        if (lane == 0) coef[l * 4 + h] = p;
    }
    {
        float rs = rsqrtf(v0[t] + 1e-5f) * g0[t];
        sAB[t] = rs;
        sAB[256 + t] = (b0[t] - m0[t]) * rs + be0[t];
    }
    {
        float rs = rsqrtf(v1[t] + 1e-5f) * g1[t];
        sAB[512 + t] = rs;
        sAB[768 + t] = (b1[t] - m1[t]) * rs + be1[t];
    }
    if (t < 64) {
        float rs = rsqrtf(v2[t] + 1e-5f) * g2[t];
        sAB[1024 + t] = rs;
        sAB[1088 + t] = (b2[t] - m2[t]) * rs + be2[t];
    }
}

// ---------------- converters: x + all three weights in one launch ----------------
__global__ __launch_bounds__(256) void k_cvt_all(const float* __restrict__ x,
                                                 const float* __restrict__ w0,
                                                 const float* __restrict__ w1,
                                                 const float* __restrict__ w2,
                                                 _Float16* __restrict__ xh,
                                                 _Float16* __restrict__ wt0,
                                                 _Float16* __restrict__ wt1,
                                                 _Float16* __restrict__ wt2,
                                                 int nvalid_rows, int xtotal) {
    const int S0 = 256 * 32, S1 = 256 * 256;
    int i = blockIdx.x * 256 + threadIdx.x;
    if (i < xtotal) {
        int r = i / 32;
        xh[i] = (r < nvalid_rows) ? (_Float16)x[i] : (_Float16)0.f;
        return;
    }
    int j = i - xtotal;
    if (j < S0) {
        int c = j / 32, k = j - c * 32;
        wt0[j] = (_Float16)w0[k * 256 + c];
    } else if (j < S0 + S1) {
        int q = j - S0;
        int c = q / 256, k = q - c * 256;
        wt1[q] = (_Float16)w1[k * 256 + c];
    } else if (j < S0 + 2 * S1) {
        int q = j - S0 - S1;
        int c = q / 256, k = q - c * 256;
        wt2[q] = (_Float16)w2[k * 256 + c];
    }
}

// ---------------- MFMA GEMM: Out[N,256] = A[N,K] @ W[K,256]
// A fp16 [Npad,K] staged into padded LDS tile (64 rows); Wt fp16 [256,K]
// (transposed) direct from global (L2-hot); Out fp16; fused fp32 ssrc/sdst.
template <int KT>
__global__ __launch_bounds__(256) void k_gemm_mfma(const _Float16* __restrict__ A,
                                                   const _Float16* __restrict__ Wt,
                                                   _Float16* __restrict__ Out, int nrows,
                                                   const float* __restrict__ as_,
                                                   const float* __restrict__ ad_,
                                                   float* __restrict__ ssrc,
                                                   float* __restrict__ sdst) {
    constexpr int STRIDE = KT + 8;          // halfs
    __shared__ _Float16 As[64 * STRIDE];
    const int tid = threadIdx.x;
    const int lane = tid & 63, wc = tid >> 6;
    const int l15 = lane & 15, g = lane >> 4;
    const int row0 = blockIdx.x * 64;

    // stage A tile [64][KT] -> LDS (coalesced 16B loads, padded rows)
    {
        constexpr int CPR = KT / 8;          // 16B chunks per row
        constexpr int CHUNKS = 64 * CPR;
#pragma unroll
        for (int c = tid; c < CHUNKS; c += 256) {
            int r = c / CPR;
            int kc = (c - r * CPR) * 8;
            half8 v = *(const half8*)(A + (size_t)(row0 + r) * KT + kc);
            *(half8*)(As + r * STRIDE + kc) = v;
        }
    }
    __syncthreads();

    f32x4 acc[4][4] = {};   // [m-frag][n-frag]
    const _Float16* Wb = Wt + (size_t)(wc * 64 + l15) * KT + g * 8;
    const _Float16* Ab = As + l15 * STRIDE + g * 8;

#pragma unroll
    for (int kk = 0; kk < KT; kk += 32) {
        half8 af[4], bf[4];
#pragma unroll
        for (int m = 0; m < 4; ++m)
            af[m] = *(const half8*)(Ab + m * 16 * STRIDE + kk);
#pragma unroll
        for (int f = 0; f < 4; ++f)
            bf[f] = *(const half8*)(Wb + (size_t)f * 16 * KT + kk);
#pragma unroll
        for (int m = 0; m < 4; ++m)
#pragma unroll
            for (int f = 0; f < 4; ++f)
                acc[m][f] = __builtin_amdgcn_mfma_f32_16x16x32_f16(af[m], bf[f], acc[m][f], 0, 0, 0);
    }

    float asv[4], adv[4];
#pragma unroll
    for (int f = 0; f < 4; ++f) {
        asv[f] = as_[wc * 64 + f * 16 + l15];
        adv[f] = ad_[wc * 64 + f * 16 + l15];
    }

#pragma unroll
    for (int m = 0; m < 4; ++m) {
        float ps[4] = {}, pd[4] = {};
#pragma unroll
        for (int f = 0; f < 4; ++f)
#pragma unroll
            for (int j = 0; j < 4; ++j) {
                ps[j] = fmaf(acc[m][f][j], asv[f], ps[j]);
                pd[j] = fmaf(acc[m][f][j], adv[f], pd[j]);
            }
#pragma unroll
        for (int o = 1; o < 16; o <<= 1)
#pragma unroll
            for (int j = 0; j < 4; ++j) {
                ps[j] += __shfl_xor(ps[j], o, 64);
                pd[j] += __shfl_xor(pd[j], o, 64);
            }
        if (l15 == 0) {
#pragma unroll
            for (int j = 0; j < 4; ++j) {
                int r = row0 + m * 16 + g * 4 + j;
                if (r < nrows) {
                    ssrc[r * 4 + wc] = ps[j];
                    sdst[r * 4 + wc] = pd[j];
                }
            }
        }
#pragma unroll
        for (int f = 0; f < 4; ++f)
#pragma unroll
            for (int j = 0; j < 4; ++j) {
                int r = row0 + m * 16 + g * 4 + j;
                if (r < nrows)
                    Out[(size_t)r * 256 + wc * 64 + f * 16 + l15] = (_Float16)acc[m][f][j];
            }
    }
}

// ---------------- fused softmax + aggregation: ONE NODE PER WAVE ----------------
// Fast path (deg<=16): load csrc indices, ISSUE all feature gathers first, then
//   compute the wave-parallel softmax while the gathers are in flight, then FMAs.
//   Clamped unconditional loads (pk==0 kills k>=deg). Branches are wave-uniform.
// Slow path (deg>16, ~0.1%): serial online softmax.
template <bool MEAN>
__global__ __launch_bounds__(256) void k_agg(const _Float16* __restrict__ hlin,
                                             const int* __restrict__ offs,
                                             const int* __restrict__ csrc,
                                             const float* __restrict__ cea,
                                             const float* __restrict__ ssrc,
                                             const float* __restrict__ sdst,
                                             const float* __restrict__ coef,
                                             const float* __restrict__ sA,
                                             const float* __restrict__ sB,
                                             _Float16* __restrict__ outh,
                                             float* __restrict__ outf, int Nn) {
    int n = blockIdx.x * 4 + (threadIdx.x >> 6);
    if (n >= Nn) return;
    int lane = threadIdx.x & 63;
    int h = lane >> 4, s = lane & 15;
    int b = offs[n], e = offs[n + 1];
    int deg = e - b;
    float sd = sdst[n * 4 + h], cf = coef[h];
    const _Float16* hrow = hlin + lane * 4;

    f32x4 acc = {};
    float inv;

    if (deg <= 16) {
        bool big = deg > 8;                 // wave-uniform
        // 1) index loads (uniform addresses -> L1 broadcast)
        int idx[8];
#pragma unroll
        for (int k = 0; k < 8; ++k) {
            int kc = k < deg ? k : deg - 1;
            idx[k] = csrc[b + kc];
        }
        // 2) issue feature gathers EARLY (latency overlaps softmax below)
        half4 hv[8], hv2[8];
#pragma unroll
        for (int k = 0; k < 8; ++k)
            hv[k] = *(const half4*)(hrow + (size_t)idx[k] * 256);
        if (big) {
            int idx2[8];
#pragma unroll
            for (int k = 0; k < 8; ++k) {
                int kk = 8 + k;
                int kc = kk < deg ? kk : deg - 1;
                idx2[k] = csrc[b + kc];
            }
#pragma unroll
            for (int k = 0; k < 8; ++k)
                hv2[k] = *(const half4*)(hrow + (size_t)idx2[k] * 256);
        }
        // 3) wave-parallel softmax while gathers are in flight
        float a0 = -INFINITY;
        if (s < deg) {
            int i = b + s;
            float a = ssrc[csrc[i] * 4 + h] + sd + cf * cea[i];
            a0 = a > 0.f ? a : 0.2f * a;                  // leaky_relu 0.2
        }
        float m = a0;
#pragma unroll
        for (int o = 1; o < 16; o <<= 1) m = fmaxf(m, __shfl_xor(m, o, 64));
        float p = (s < deg) ? __expf(a0 - m) : 0.f;
        float den = p;
#pragma unroll
        for (int o = 1; o < 16; o <<= 1) den += __shfl_xor(den, o, 64);
        inv = 1.f / den;

        // 4) FMAs
#pragma unroll
        for (int k = 0; k < 8; ++k) {
            float pk = __shfl(p, (h << 4) | k, 64);
#pragma unroll
            for (int j = 0; j < 4; ++j) acc[j] = fmaf(pk, (float)hv[k][j], acc[j]);
        }
        if (big) {
#pragma unroll
            for (int k = 0; k < 8; ++k) {
                float pk = __shfl(p, (h << 4) | (8 + k), 64);
#pragma unroll
                for (int j = 0; j < 4; ++j) acc[j] = fmaf(pk, (float)hv2[k][j], acc[j]);
            }
        }
    } else {
        // rare fallback: serial online softmax
        float m = -INFINITY, den = 0.f;
        for (int i = b; i < e; ++i) {
            int sn = csrc[i];
            float a = ssrc[sn * 4 + h] + sd + cf * cea[i];
            a = a > 0.f ? a : 0.2f * a;
            float mn = fmaxf(m, a);
            float sc = __expf(m - mn);
            float p = __expf(a - mn);
            den = den * sc + p;
            half4 hv = *(const half4*)(hrow + (size_t)sn * 256);
#pragma unroll
            for (int j = 0; j < 4; ++j) acc[j] = acc[j] * sc + p * (float)hv[j];
            m = mn;
        }
        inv = 1.f / den;
    }

    if (!MEAN) {
        int c = lane * 4;
        float4 a4 = *(const float4*)&sA[c];
        float4 b4 = *(const float4*)&sB[c];
        half4 o;
#pragma unroll
        for (int j = 0; j < 4; ++j) {
            float v = acc[j] * inv * (&a4.x)[j] + (&b4.x)[j];
            v = v > 0.f ? v : expm1f(v);                  // ELU
            o[j] = (_Float16)v;
        }
        *(half4*)(outh + (size_t)n * 256 + c) = o;
    } else {
        float r[4];
#pragma unroll
        for (int j = 0; j < 4; ++j) {
            r[j] = acc[j] * inv;
            r[j] += __shfl_xor(r[j], 16, 64);
            r[j] += __shfl_xor(r[j], 32, 64);             // sum over 4 heads
        }
        if (lane < 16) {
            int c = lane * 4;
#pragma unroll
            for (int j = 0; j < 4; ++j) {
                float v = 0.25f * r[j] * sA[c + j] + sB[c + j];
                outf[(size_t)n * 64 + c + j] = v;
            }
        }
    }
}

// ---------------- graph pooling: segmented (batch is sorted) ----------------
__global__ __launch_bounds__(256) void k_pool(const float* __restrict__ h2,
                                              const int* __restrict__ batch,
                                              float* __restrict__ psum,
                                              unsigned* __restrict__ pmaxk,
                                              float* __restrict__ pcnt, int Nn) {
    int wglob = blockIdx.x * 4 + (threadIdx.x >> 6);
    int lane = threadIdx.x & 63;
    int nwaves = gridDim.x * 4;
    int span = (Nn + nwaves - 1) / nwaves;
    int b = wglob * span, e = min(b + span, Nn);
    if (b >= e) return;
    int curg = batch[b];
    float s = 0.f, mx = -INFINITY;
    float cnt = 0.f;
    for (int i = b; i < e; ++i) {
        int g = batch[i];
        float v = h2[(size_t)i * 64 + lane];
        if (g != curg) {
            atomicAdd(&psum[curg * 64 + lane], s);
            atomicMax(&pmaxk[curg * 64 + lane], fkey(mx));
            if (lane == 0) atomicAdd(&pcnt[curg], cnt);
            s = 0.f; mx = -INFINITY; cnt = 0.f; curg = g;
        }
        s += v; mx = fmaxf(mx, v); cnt += 1.f;
    }
    atomicAdd(&psum[curg * 64 + lane], s);
    atomicMax(&pmaxk[curg * 64 + lane], fkey(mx));
    if (lane == 0) atomicAdd(&pcnt[curg], cnt);
}

// ---------------- MLP head ----------------
__global__ __launch_bounds__(128) void k_mlp(const float* __restrict__ psum,
                                             const unsigned* __restrict__ pmaxk,
                                             const float* __restrict__ pcnt,
                                             const float* __restrict__ emb,
                                             const int* __restrict__ cids,
                                             const float* __restrict__ mw1, const float* __restrict__ mb1,
                                             const float* __restrict__ mw2, const float* __restrict__ mb2,
                                             const float* __restrict__ mw3, const float* __restrict__ mb3,
                                             float* __restrict__ out) {
    __shared__ float comb[144];
    __shared__ float z1[128];
    __shared__ float z2[64];
    int g = blockIdx.x, t = threadIdx.x;
    float cnt = fmaxf(pcnt[g], 1.f);
    if (t < 64) {
        comb[t] = psum[g * 64 + t] / cnt;
        comb[64 + t] = fdecode(pmaxk[g * 64 + t]);
    }
    if (t < 16) comb[128 + t] = emb[cids[g] * 16 + t];
    __syncthreads();
    float a = mb1[t];
    for (int k = 0; k < 144; ++k) a = fmaf(comb[k], mw1[k * 128 + t], a);
    z1[t] = fmaxf(a, 0.f);
    __syncthreads();
    if (t < 64) {
        float a2 = mb2[t];
        for (int k = 0; k < 128; ++k) a2 = fmaf(z1[k], mw2[k * 64 + t], a2);
        z2[t] = fmaxf(a2, 0.f);
    }
    __syncthreads();
    if (t < 2) {
        float a3 = mb3[t];
        for (int k = 0; k < 64; ++k) a3 = fmaf(z2[k], mw3[k * 2 + t], a3);
        out[g * 2 + t] = a3;
    }
}

extern "C" void kernel_launch(void* const* d_in, const int* in_sizes, int n_in,
                              void* d_out, int out_size, void* d_ws, size_t ws_size,
                              hipStream_t stream) {
    const float* x         = (const float*)d_in[0];
    const float* edge_attr = (const float*)d_in[1];
    const float* w0  = (const float*)d_in[2];
    const float* as0 = (const float*)d_in[3];
    const float* ad0 = (const float*)d_in[4];
    const float* we0 = (const float*)d_in[5];
    const float* ae0 = (const float*)d_in[6];
    const float* w1  = (const float*)d_in[7];
    const float* as1 = (const float*)d_in[8];
    const float* ad1 = (const float*)d_in[9];
    const float* we1 = (const float*)d_in[10];
    const float* ae1 = (const float*)d_in[11];
    const float* w2  = (const float*)d_in[12];
    const float* as2 = (const float*)d_in[13];
    const float* ad2 = (const float*)d_in[14];
    const float* we2 = (const float*)d_in[15];
    const float* ae2 = (const float*)d_in[16];
    const float* b0  = (const float*)d_in[17];
    const float* b1  = (const float*)d_in[18];
    const float* b2  = (const float*)d_in[19];
    const float* bn_g0 = (const float*)d_in[20];
    const float* bn_b0 = (const float*)d_in[21];
    const float* bn_m0 = (const float*)d_in[22];
    const float* bn_v0 = (const float*)d_in[23];
    const float* bn_g1 = (const float*)d_in[24];
    const float* bn_b1 = (const float*)d_in[25];
    const float* bn_m1 = (const float*)d_in[26];
    const float* bn_v1 = (const float*)d_in[27];
    const float* bn_g2 = (const float*)d_in[28];
    const float* bn_b2 = (const float*)d_in[29];
    const float* bn_m2 = (const float*)d_in[30];
    const float* bn_v2 = (const float*)d_in[31];
    const float* emb = (const float*)d_in[32];
    const float* mw1 = (const float*)d_in[33];
    const float* mb1 = (const float*)d_in[34];
    const float* mw2 = (const float*)d_in[35];
    const float* mb2 = (const float*)d_in[36];
    const float* mw3 = (const float*)d_in[37];
    const float* mb3 = (const float*)d_in[38];
    const int* edge_index = (const int*)d_in[39];
    const int* batch      = (const int*)d_in[40];
    const int* cids       = (const int*)d_in[41];

    const int N = in_sizes[40];       // 50000
    const int E = in_sizes[1];        // 300000
    const int G = in_sizes[41];       // 128
    const int EP = E + N;
    const int NB = (N + 63) / 64;     // gemm blocks
    const int Npad = NB * 64;         // padded rows
    const int NSB = (N + 1023) / 1024; // scan blocks (<=256)

    // ---- workspace layout ----
    size_t off = 0;
    auto alloc = [&](size_t bytes) -> void* {
        void* p = (char*)d_ws + off;
        off += (bytes + 255) & ~(size_t)255;
        return p;
    };
    // zero-init prefix
    int*      counts = (int*)alloc((size_t)N * 4);
    int*      cursor = (int*)alloc((size_t)N * 4);
    float*    psum   = (float*)alloc((size_t)G * 64 * 4);
    unsigned* pmaxk  = (unsigned*)alloc((size_t)G * 64 * 4);
    float*    pcnt   = (float*)alloc((size_t)G * 4);
    float*    easum  = (float*)alloc(4);
    size_t zbytes = off;
    // rest
    int*   offs = (int*)alloc((size_t)(N + 1) * 4);
    int*   bsum = (int*)alloc(256 * 4);
    int*   csrc = (int*)alloc((size_t)EP * 4);
    float* cea  = (float*)alloc((size_t)EP * 4);
    float* ssrc = (float*)alloc((size_t)N * 4 * 4);
    float* sdst = (float*)alloc((size_t)N * 4 * 4);
    float* coef = (float*)alloc(12 * 4);
    float* sAB  = (float*)alloc(1152 * 4);
    _Float16* xh  = (_Float16*)alloc((size_t)Npad * 32 * 2);
    _Float16* wt0 = (_Float16*)alloc((size_t)256 * 32 * 2);
    _Float16* wt1 = (_Float16*)alloc((size_t)256 * 256 * 2);
    _Float16* wt2 = (_Float16*)alloc((size_t)256 * 256 * 2);
    _Float16* hH  = (_Float16*)alloc((size_t)Npad * 256 * 2);  // GEMM out (fp16, gather src)
    _Float16* hB  = (_Float16*)alloc((size_t)Npad * 256 * 2);  // agg out (fp16, GEMM in)
    float*    h2  = (float*)alloc((size_t)N * 64 * 4);         // layer-2 out
    (void)ws_size; (void)n_in; (void)out_size;

    hipMemsetAsync(d_ws, 0, zbytes, stream);

    // ---- graph preprocessing ----
    k_count<<<1024, 256, 0, stream>>>(edge_index, edge_attr, counts, easum, E, N);
    k_scan1<<<NSB, 256, 0, stream>>>(counts, offs, bsum, N);
    k_scan2<<<1, 256, 0, stream>>>(bsum, offs, NSB, EP, N);
    k_scan3<<<NSB, 256, 0, stream>>>(offs, bsum, N);
    k_scatter<<<1024, 256, 0, stream>>>(edge_index, edge_attr, easum, offs, cursor, csrc, cea, E, N);
    k_coef_prep<<<1, 256, 0, stream>>>(we0, ae0, we1, ae1, we2, ae2, coef,
                                       b0, bn_g0, bn_b0, bn_m0, bn_v0,
                                       b1, bn_g1, bn_b1, bn_m1, bn_v1,
                                       b2, bn_g2, bn_b2, bn_m2, bn_v2, sAB);

    // ---- fp16 conversions (one launch) ----
    {
        int xtotal = Npad * 32;
        int total = xtotal + 256 * 32 + 2 * 256 * 256;
        k_cvt_all<<<(total + 255) / 256, 256, 0, stream>>>(x, w0, w1, w2,
                                                           xh, wt0, wt1, wt2, N, xtotal);
    }

    int agg_grid = (N + 3) / 4;

    // ---- layer 0 ----
    k_gemm_mfma<32><<<NB, 256, 0, stream>>>(xh, wt0, hH, N, as0, ad0, ssrc, sdst);
    k_agg<false><<<agg_grid, 256, 0, stream>>>(hH, offs, csrc, cea, ssrc, sdst, coef + 0,
                                               sAB, sAB + 256, hB, nullptr, N);
    // ---- layer 1 ----
    k_gemm_mfma<256><<<NB, 256, 0, stream>>>(hB, wt1, hH, N, as1, ad1, ssrc, sdst);
    k_agg<false><<<agg_grid, 256, 0, stream>>>(hH, offs, csrc, cea, ssrc, sdst, coef + 4,
                                               sAB + 512, sAB + 768, hB, nullptr, N);
    // ---- layer 2 ----
    k_gemm_mfma<256><<<NB, 256, 0, stream>>>(hB, wt2, hH, N, as2, ad2, ssrc, sdst);
    k_agg<true><<<agg_grid, 256, 0, stream>>>(hH, offs, csrc, cea, ssrc, sdst, coef + 8,
                                              sAB + 1024, sAB + 1088, nullptr, h2, N);

    // ---- pooling + MLP head ----
    k_pool<<<512, 256, 0, stream>>>(h2, batch, psum, pmaxk, pcnt, N);
    k_mlp<<<G, 128, 0, stream>>>(psum, pmaxk, pcnt, emb, cids,
                                 mw1, mb1, mw2, mb2, mw3, mb3, (float*)d_out);
}